// Round 2
// baseline (1393.375 us; speedup 1.0000x reference)
//
#include <hip/hip_runtime.h>
#include <hip/hip_bf16.h>
#include <cstdint>
#include <cstddef>

typedef __bf16 bf16;
typedef __attribute__((ext_vector_type(8))) __bf16 bf16x8;
typedef __attribute__((ext_vector_type(4))) __bf16 bf16x4;
typedef __attribute__((ext_vector_type(4))) float f32x4;

#define DEVI __device__ __forceinline__

// Problem constants
constexpr int Bb = 256, Nn = 164, Dd = 1024, Hh = 8, DHh = 128, NKk = 100;
constexpr int Mm = Bb * Nn;   // 41984 = 328 * 128 exactly
constexpr int JP = 192;       // padded key length for PV (6 x 32)

DEVI void gl_lds16(const void* g, void* l) {
  __builtin_amdgcn_global_load_lds(
      (const __attribute__((address_space(1))) void*)g,
      (__attribute__((address_space(3))) void*)l, 16, 0, 0);
}

// swizzles: index in bf16 units. 256B rows (128 bf16, 16 slots of 8):
DEVI int sw16(int row, int kb) { return row * 128 + ((kb ^ (row & 7)) * 8); }
// 128B rows (64 bf16, 8 slots):
DEVI int sw8(int row, int kb)  { return row * 64 + ((kb ^ (row & 7)) * 8); }
// 384B rows (192 bf16, 24 slots): mod-24 rotation
DEVI int sw24(int row, int kb) { return row * 192 + (((kb + row) % 24) * 8); }

// ---------------- convert f32 -> bf16 (flat) ----------------
__global__ void k_cvt_bf16(const float* __restrict__ in, bf16* __restrict__ out, int n) {
  int stride = gridDim.x * blockDim.x;
  for (int i = blockIdx.x * blockDim.x + threadIdx.x; i < (n >> 2); i += stride) {
    float4 v = ((const float4*)in)[i];
    bf16x4 o;
    o[0] = (bf16)v.x; o[1] = (bf16)v.y; o[2] = (bf16)v.z; o[3] = (bf16)v.w;
    ((bf16x4*)out)[i] = o;
  }
}

// ---------------- mask dtype detection ----------------
// mode: 1 = byte-storage (uint8/bool), 0 = int32, 2 = int64
__global__ void k_maskdet(const unsigned char* __restrict__ m, int* __restrict__ mode) {
  __shared__ int sbyte, sodd;
  if (threadIdx.x == 0) { sbyte = 0; sodd = 0; }
  __syncthreads();
  for (int i = threadIdx.x; i < Mm; i += 256)
    if ((i & 3) && m[i]) sbyte = 1;           // benign race
  __syncthreads();
  if (sbyte == 0) {
    const int* m32 = (const int*)m;
    for (int i = 1 + 2 * (int)threadIdx.x; i < Mm; i += 512)
      if (m32[i] != 0) sodd = 1;              // odd int32 lanes: 0 iff int64 storage
  }
  __syncthreads();
  if (threadIdx.x == 0) *mode = sbyte ? 1 : (sodd ? 0 : 2);
}

// ---------------- transpose + convert: in (R x C f32) -> out (C x R bf16) ----------------
__global__ void k_transpose_cvt(const float* __restrict__ in, bf16* __restrict__ out,
                                int R, int C) {
  __shared__ float tile[32][33];
  int c0 = blockIdx.x * 32, r0 = blockIdx.y * 32;
  int tx = threadIdx.x & 31, ty = threadIdx.x >> 5;  // 32 x 8
#pragma unroll
  for (int i = 0; i < 4; ++i) {
    int r = ty + i * 8;
    tile[r][tx] = in[(size_t)(r0 + r) * C + c0 + tx];
  }
  __syncthreads();
#pragma unroll
  for (int i = 0; i < 4; ++i) {
    int rr = ty + i * 8;  // col index of input
    out[(size_t)(c0 + rr) * R + r0 + tx] = (bf16)tile[tx][rr];
  }
}

// ---------------- v transpose: qkv v-region [m][dh] -> vT [bh][dh][JP] (zero-padded j>=164) ----
__global__ void k_vT(const bf16* __restrict__ qkv, bf16* __restrict__ vT) {
  __shared__ bf16 t[32][33];
  int bh = blockIdx.y; int b = bh >> 3, h = bh & 7;
  int jt = blockIdx.x % 6, dt = blockIdx.x / 6;
  int tx = threadIdx.x & 31, ty = threadIdx.x >> 5;
#pragma unroll
  for (int i = 0; i < 4; ++i) {
    int j = jt * 32 + ty + i * 8;
    bf16 val = (bf16)0.f;
    if (j < 164) val = qkv[(size_t)(b * 164 + j) * 3072 + 2048 + h * 128 + dt * 32 + tx];
    t[ty + i * 8][tx] = val;
  }
  __syncthreads();
#pragma unroll
  for (int i = 0; i < 4; ++i) {
    int dh = dt * 32 + ty + i * 8;
    vT[((size_t)bh * 128 + dh) * JP + jt * 32 + tx] = t[tx][ty + i * 8];
  }
}

// ---------------- GEMM: C(MxN) = A(MxK) * Bt(NxK)^T,  K=1024, 128x128 tile, BK=32 ----------
// MODE 0: C bf16 (ld 3072).  MODE 1: C f32 + bias (ld 1024).
template <int MODE>
__global__ __launch_bounds__(256) void k_gemm(const bf16* __restrict__ A,
                                              const bf16* __restrict__ Bt,
                                              void* __restrict__ Cout,
                                              const float* __restrict__ bias) {
  constexpr int K = 1024;
  constexpr int CLD = (MODE == 0) ? 3072 : 1024;
  __shared__ bf16 As[128 * 32];
  __shared__ bf16 Bs[128 * 32];
  const int tid = threadIdx.x, lane = tid & 63, w = tid >> 6;
  const int l15 = lane & 15, l4 = lane >> 4;
  const int wm = w >> 1, wn = w & 1;
  const int tileM = blockIdx.y * 128, tileN = blockIdx.x * 128;

  f32x4 acc[4][4];
#pragma unroll
  for (int mi = 0; mi < 4; ++mi)
#pragma unroll
    for (int ni = 0; ni < 4; ++ni) acc[mi][ni] = f32x4{0.f, 0.f, 0.f, 0.f};

  for (int k0 = 0; k0 < K; k0 += 32) {
    __syncthreads();
#pragma unroll
    for (int i = 0; i < 2; ++i) {
      int c = w * 2 + i;
      int blk = c * 64 + lane;
      int r = blk >> 2, sl = blk & 3;
      int kb = sl ^ ((r >> 1) & 3);
      gl_lds16(A + (size_t)(tileM + r) * K + k0 + kb * 8, (char*)As + c * 1024);
      gl_lds16(Bt + (size_t)(tileN + r) * K + k0 + kb * 8, (char*)Bs + c * 1024);
    }
    __syncthreads();
    bf16x8 af[4], bfr[4];
#pragma unroll
    for (int mi = 0; mi < 4; ++mi) {
      int r = wm * 64 + mi * 16 + l15;
      af[mi] = *(const bf16x8*)&As[r * 32 + ((l4 ^ ((r >> 1) & 3)) * 8)];
    }
#pragma unroll
    for (int ni = 0; ni < 4; ++ni) {
      int r = wn * 64 + ni * 16 + l15;
      bfr[ni] = *(const bf16x8*)&Bs[r * 32 + ((l4 ^ ((r >> 1) & 3)) * 8)];
    }
#pragma unroll
    for (int mi = 0; mi < 4; ++mi)
#pragma unroll
      for (int ni = 0; ni < 4; ++ni)
        acc[mi][ni] = __builtin_amdgcn_mfma_f32_16x16x32_bf16(af[mi], bfr[ni], acc[mi][ni], 0, 0, 0);
  }

#pragma unroll
  for (int mi = 0; mi < 4; ++mi)
#pragma unroll
    for (int ni = 0; ni < 4; ++ni)
#pragma unroll
      for (int j = 0; j < 4; ++j) {
        int m = tileM + wm * 64 + mi * 16 + l4 * 4 + j;
        int n = tileN + wn * 64 + ni * 16 + l15;
        float v = acc[mi][ni][j];
        if (MODE == 0)
          ((bf16*)Cout)[(size_t)m * CLD + n] = (bf16)v;
        else
          ((float*)Cout)[(size_t)m * CLD + n] = v + bias[n];
      }
}

// ---------------- fused attention ----------------
// grid: (3 qtiles, 2048 bh), 256 threads.
__global__ __launch_bounds__(256) void k_attn(
    const bf16* __restrict__ qkv, const bf16* __restrict__ vT,
    const void* __restrict__ maskp, const int* __restrict__ maskmode,
    const float* __restrict__ xian,
    const float* __restrict__ W1, const float* __restrict__ b1,
    const float* __restrict__ W2, const float* __restrict__ b2,
    bf16* __restrict__ aout) {
  // LDS map (bytes):
  //  [0,16384)        Qs  [64][128] bf16 sw16      -- phase QK
  //  [16384,61440)    Ks  [176][128] bf16 sw16     -- phase QK
  //  [0,49152)        VTs [128][192] bf16 sw24     -- overlays Qs/Ks after QK^T
  //  [61440,106496)   Ss  [64][176] f32
  //  [106496,131072)  Ps  [64][192] bf16 sw24 ; first 16KB doubles as AQs [64][128] sw16
  //  [131072,147456)  W1T [64][128] bf16 sw16 ; overlaid by H1s [64][64] sw8 after L1
  //  [147456,161792)  W2T [112][64] bf16 sw8
  __shared__ __align__(16) char smem[161792];
  bf16* Qs  = (bf16*)smem;
  bf16* Ks  = (bf16*)(smem + 16384);
  bf16* VTs = (bf16*)smem;
  float* Ss = (float*)(smem + 61440);
  bf16* Ps  = (bf16*)(smem + 106496);
  bf16* AQs = (bf16*)(smem + 106496);
  bf16* W1T = (bf16*)(smem + 131072);
  bf16* W2T = (bf16*)(smem + 147456);
  bf16* H1s = (bf16*)(smem + 131072);

  const int tid = threadIdx.x, lane = tid & 63, w = tid >> 6;
  const int l15 = lane & 15, l4 = lane >> 4;
  const int qt = blockIdx.x, bh = blockIdx.y, b = bh >> 3, h = bh & 7;
  const int mmode = *maskmode;

  // ---- Phase 0: stage Q (64x128) and K (164x128 + 12 zero rows), W1T/W2T ----
#pragma unroll
  for (int i = 0; i < 4; ++i) {
    int c = w * 4 + i;
    int blk = c * 64 + lane;
    int r = blk >> 4, sl = blk & 15;
    int kb = sl ^ (r & 7);
    int gi = qt * 64 + r; if (gi > 163) gi = 163;
    gl_lds16(qkv + (size_t)(b * 164 + gi) * 3072 + h * 128 + kb * 8, (char*)Qs + c * 1024);
  }
  for (int c = w; c < 41; c += 4) {
    int blk = c * 64 + lane;
    int r = blk >> 4, sl = blk & 15;
    int kb = sl ^ (r & 7);
    gl_lds16(qkv + (size_t)(b * 164 + r) * 3072 + 1024 + h * 128 + kb * 8, (char*)Ks + c * 1024);
  }
  if (tid < 192) {  // zero K pad rows 164..175
    int r = 164 + (tid >> 4), sl = tid & 15;
    ((int4*)Ks)[r * 16 + sl] = make_int4(0, 0, 0, 0);
  }
  {   // zero W1T/W2T region (30720 B)
    int4 z = make_int4(0, 0, 0, 0);
    for (int i = tid; i < 1920; i += 256) ((int4*)(smem + 131072))[i] = z;
  }
  __syncthreads();
  for (int idx = tid; idx < 5000; idx += 256) {   // W1 [100][50] -> W1T rows=c cols=j
    int j = idx / 50, c = idx % 50;
    W1T[sw16(c, j >> 3) + (j & 7)] = (bf16)W1[idx];
  }
  for (int idx = tid; idx < 5000; idx += 256) {   // W2 [50][100] -> W2T rows=j' cols=c
    int c = idx / 100, jp = idx % 100;
    W2T[sw8(jp, c >> 3) + (c & 7)] = (bf16)W2[idx];
  }
  __syncthreads();

  // ---- Phase 1: S = Q K^T * scale ----
  f32x4 accs[11];
#pragma unroll
  for (int nt = 0; nt < 11; ++nt) accs[nt] = f32x4{0.f, 0.f, 0.f, 0.f};
#pragma unroll
  for (int kk = 0; kk < 4; ++kk) {
    bf16x8 af = *(const bf16x8*)&Qs[sw16(w * 16 + l15, kk * 4 + l4)];
#pragma unroll
    for (int nt = 0; nt < 11; ++nt) {
      bf16x8 bb = *(const bf16x8*)&Ks[sw16(nt * 16 + l15, kk * 4 + l4)];
      accs[nt] = __builtin_amdgcn_mfma_f32_16x16x32_bf16(af, bb, accs[nt], 0, 0, 0);
    }
  }
  constexpr float SC = 0.03125f;  // D^-0.5
#pragma unroll
  for (int nt = 0; nt < 11; ++nt)
#pragma unroll
    for (int j = 0; j < 4; ++j)
      Ss[(w * 16 + l4 * 4 + j) * 176 + nt * 16 + l15] = accs[nt][j] * SC;
  __syncthreads();

  // ---- Phase 2: VT stage (async) + mask + AQ fill ----
  for (int c = w; c < 48; c += 4) {
    int blk = c * 64 + lane;
    int dh = blk / 24, sl = blk % 24;
    int kb = sl - (dh % 24); if (kb < 0) kb += 24;
    gl_lds16(vT + ((size_t)bh * 128 + dh) * JP + kb * 8, (char*)VTs + c * 1024);
  }
  {
    const unsigned char* m8 = (const unsigned char*)maskp;
    const int* m32 = (const int*)maskp;
    const long long* m64 = (const long long*)maskp;
    int row = tid >> 2, c0 = (tid & 3) * 44;
    for (int cc = 0; cc < 44; ++cc) {
      int col = c0 + cc;
      bool killed = (col >= 164);
      if (!killed && col >= NKk) {
        int mi = b * 164 + col;
        long long mv = (mmode == 1) ? (long long)m8[mi]
                     : (mmode == 0) ? (long long)m32[mi]
                                    : m64[mi];
        killed = (mv != 0);
      }
      if (killed) Ss[row * 176 + col] = -__FLT_MAX__;
    }
  }
  if (qt < 2) {
    int row = tid >> 2, c0 = (tid & 3) * 32;
    for (int cc = 0; cc < 32; ++cc) {
      int col = c0 + cc;
      float v = (col < NKk) ? fmaxf(Ss[row * 176 + col], 0.f) : 0.f;
      AQs[sw16(row, col >> 3) + (col & 7)] = (bf16)v;
    }
  }
  __syncthreads();

  // ---- Phase 3: MLP via MFMA (only qtiles containing rows < 100) ----
  if (qt < 2) {
    f32x4 a1[4];
#pragma unroll
    for (int nt = 0; nt < 4; ++nt) a1[nt] = f32x4{0.f, 0.f, 0.f, 0.f};
#pragma unroll
    for (int kk = 0; kk < 4; ++kk) {
      bf16x8 af = *(const bf16x8*)&AQs[sw16(w * 16 + l15, kk * 4 + l4)];
#pragma unroll
      for (int nt = 0; nt < 4; ++nt) {
        bf16x8 bb = *(const bf16x8*)&W1T[sw16(nt * 16 + l15, kk * 4 + l4)];
        a1[nt] = __builtin_amdgcn_mfma_f32_16x16x32_bf16(af, bb, a1[nt], 0, 0, 0);
      }
    }
    __syncthreads();  // all waves done reading W1T before H1s overlay
#pragma unroll
    for (int nt = 0; nt < 4; ++nt)
#pragma unroll
      for (int j = 0; j < 4; ++j) {
        int row = w * 16 + l4 * 4 + j, c = nt * 16 + l15;
        float hv = (c < 50) ? fmaxf(a1[nt][j] + b1[c], 0.f) : 0.f;
        H1s[sw8(row, c >> 3) + (c & 7)] = (bf16)hv;
      }
    __syncthreads();
    f32x4 a2[7];
#pragma unroll
    for (int nt = 0; nt < 7; ++nt) a2[nt] = f32x4{0.f, 0.f, 0.f, 0.f};
#pragma unroll
    for (int kk = 0; kk < 2; ++kk) {
      bf16x8 af = *(const bf16x8*)&H1s[sw8(w * 16 + l15, kk * 4 + l4)];
#pragma unroll
      for (int nt = 0; nt < 7; ++nt) {
        bf16x8 bb = *(const bf16x8*)&W2T[sw8(nt * 16 + l15, kk * 4 + l4)];
        a2[nt] = __builtin_amdgcn_mfma_f32_16x16x32_bf16(af, bb, a2[nt], 0, 0, 0);
      }
    }
#pragma unroll
    for (int nt = 0; nt < 7; ++nt)
#pragma unroll
      for (int j = 0; j < 4; ++j) {
        int row = w * 16 + l4 * 4 + j, jp = nt * 16 + l15;
        int gi = qt * 64 + row;
        if (gi < NKk && jp < NKk) {
          float lv = fmaxf(a2[nt][j] + b2[jp], 0.f);
          Ss[row * 176 + jp] += xian[((size_t)b * 100 + gi) * 100 + jp] * lv;
        }
      }
  }
  __syncthreads();

  // ---- Phase 4: softmax rows, write P (bf16) ----
  {
    int row = tid >> 2, q4 = tid & 3;
    float* srow = &Ss[row * 176];
    float mx = -__FLT_MAX__;
    for (int cc = 0; cc < 44; ++cc) mx = fmaxf(mx, srow[q4 * 44 + cc]);
    mx = fmaxf(mx, __shfl_xor(mx, 1));
    mx = fmaxf(mx, __shfl_xor(mx, 2));
    float sum = 0.f;
    for (int cc = 0; cc < 44; ++cc) {
      float e = __expf(srow[q4 * 44 + cc] - mx);
      srow[q4 * 44 + cc] = e;
      sum += e;
    }
    sum += __shfl_xor(sum, 1);
    sum += __shfl_xor(sum, 2);
    float rinv = 1.f / sum;
    for (int cc = 0; cc < 44; ++cc) {
      int col = q4 * 44 + cc;
      Ps[sw24(row, col >> 3) + (col & 7)] = (bf16)(srow[col] * rinv);
    }
    if (q4 == 3) {
#pragma unroll
      for (int col = 176; col < 192; ++col)
        Ps[sw24(row, col >> 3) + (col & 7)] = (bf16)0.f;
    }
  }
  __syncthreads();

  // ---- Phase 5: O = P V  (K padded to 192; P zero / VT zero there) ----
  f32x4 ao[8];
#pragma unroll
  for (int nt = 0; nt < 8; ++nt) ao[nt] = f32x4{0.f, 0.f, 0.f, 0.f};
#pragma unroll
  for (int kk = 0; kk < 6; ++kk) {
    bf16x8 af = *(const bf16x8*)&Ps[sw24(w * 16 + l15, kk * 4 + l4)];
#pragma unroll
    for (int nt = 0; nt < 8; ++nt) {
      bf16x8 bb = *(const bf16x8*)&VTs[sw24(nt * 16 + l15, kk * 4 + l4)];
      ao[nt] = __builtin_amdgcn_mfma_f32_16x16x32_bf16(af, bb, ao[nt], 0, 0, 0);
    }
  }
#pragma unroll
  for (int nt = 0; nt < 8; ++nt)
#pragma unroll
    for (int j = 0; j < 4; ++j) {
      int row = w * 16 + l4 * 4 + j;
      int gi = qt * 64 + row;
      if (gi < 164) {
        int dh = nt * 16 + l15;
        aout[(size_t)(b * 164 + gi) * 1024 + h * 128 + dh] = (bf16)ao[nt][j];
      }
    }
}

// ---------------- launch ----------------
extern "C" void kernel_launch(void* const* d_in, const int* in_sizes, int n_in,
                              void* d_out, int out_size, void* d_ws, size_t ws_size,
                              hipStream_t stream) {
  const float* x    = (const float*)d_in[0];
  const void* mask  = (const void*)d_in[1];
  const float* xian = (const float*)d_in[2];
  const float* Wqkv = (const float*)d_in[3];
  const float* W1   = (const float*)d_in[4];
  const float* b1   = (const float*)d_in[5];
  const float* W2   = (const float*)d_in[6];
  const float* b2   = (const float*)d_in[7];
  const float* Wout = (const float*)d_in[8];
  const float* bout = (const float*)d_in[9];
  float* out = (float*)d_out;
  char* ws = (char*)d_ws;

  // workspace layout (bytes); total 538,968,064 (~514 MiB)
  bf16* xb    = (bf16*)(ws);                    // [41984][1024]
  bf16* wqkvT = (bf16*)(ws + 85983232ULL);      // [3072][1024]
  bf16* woutT = (bf16*)(ws + 92274688ULL);      // [1024][1024]
  bf16* qkvb  = (bf16*)(ws + 94371840ULL);      // [41984][3072]
  bf16* vTb   = (bf16*)(ws + 352321536ULL);     // [2048][128][192]
  bf16* aoutb = (bf16*)(ws + 452984832ULL);     // [41984][1024]
  int*  mmode = (int*)(ws);                     // reuses xb region (dead after GEMM1)

  k_cvt_bf16<<<2048, 256, 0, stream>>>(x, xb, Mm * 1024);
  k_transpose_cvt<<<dim3(96, 32), 256, 0, stream>>>(Wqkv, wqkvT, 1024, 3072);
  k_transpose_cvt<<<dim3(32, 32), 256, 0, stream>>>(Wout, woutT, 1024, 1024);
  k_gemm<0><<<dim3(24, 328), 256, 0, stream>>>(xb, wqkvT, (void*)qkvb, nullptr);
  k_maskdet<<<1, 256, 0, stream>>>((const unsigned char*)mask, mmode);
  k_vT<<<dim3(24, 2048), 256, 0, stream>>>(qkvb, vTb);
  k_attn<<<dim3(3, 2048), 256, 0, stream>>>(qkvb, vTb, mask, mmode, xian, W1, b1, W2, b2, aoutb);
  k_gemm<1><<<dim3(8, 328), 256, 0, stream>>>(aoutb, woutT, (void*)out, bout);
}

// Round 3
// 1133.875 us; speedup vs baseline: 1.2289x; 1.2289x over previous
//
#include <hip/hip_runtime.h>
#include <hip/hip_bf16.h>
#include <cstdint>
#include <cstddef>

typedef __bf16 bf16;
typedef __attribute__((ext_vector_type(8))) __bf16 bf16x8;
typedef __attribute__((ext_vector_type(4))) __bf16 bf16x4;
typedef __attribute__((ext_vector_type(4))) float f32x4;

#define DEVI __device__ __forceinline__

constexpr int Bb = 256, Nn = 164, NKk = 100;
constexpr int Mm = Bb * Nn;   // 41984
constexpr int JP = 192;

DEVI void gl_lds16(const void* g, void* l) {
  __builtin_amdgcn_global_load_lds(
      (const __attribute__((address_space(1))) void*)g,
      (__attribute__((address_space(3))) void*)l, 16, 0, 0);
}

DEVI int sw16(int row, int kb) { return row * 128 + ((kb ^ (row & 7)) * 8); }
DEVI int sw8(int row, int kb)  { return row * 64 + ((kb ^ (row & 7)) * 8); }

// ---------------- convert f32 -> bf16 (flat) ----------------
__global__ void k_cvt_bf16(const float* __restrict__ in, bf16* __restrict__ out, int n) {
  int stride = gridDim.x * blockDim.x;
  for (int i = blockIdx.x * blockDim.x + threadIdx.x; i < (n >> 2); i += stride) {
    float4 v = ((const float4*)in)[i];
    bf16x4 o;
    o[0] = (bf16)v.x; o[1] = (bf16)v.y; o[2] = (bf16)v.z; o[3] = (bf16)v.w;
    ((bf16x4*)out)[i] = o;
  }
}

// ---------------- mask dtype detection ----------------
__global__ void k_maskdet(const unsigned char* __restrict__ m, int* __restrict__ mode) {
  __shared__ int sbyte, sodd;
  if (threadIdx.x == 0) { sbyte = 0; sodd = 0; }
  __syncthreads();
  for (int i = threadIdx.x; i < Mm; i += 256)
    if ((i & 3) && m[i]) sbyte = 1;
  __syncthreads();
  if (sbyte == 0) {
    const int* m32 = (const int*)m;
    for (int i = 1 + 2 * (int)threadIdx.x; i < Mm; i += 512)
      if (m32[i] != 0) sodd = 1;
  }
  __syncthreads();
  if (threadIdx.x == 0) *mode = sbyte ? 1 : (sodd ? 0 : 2);
}

// ---------------- prep: W1T/W2T swizzled bf16 LDS-images in global ----------------
__global__ void k_prep_w(const float* __restrict__ W1, const float* __restrict__ W2,
                         bf16* __restrict__ w1t, bf16* __restrict__ w2t) {
  int tid = threadIdx.x;
  int4 z = make_int4(0, 0, 0, 0);
  for (int i = tid; i < 1024; i += 256) ((int4*)w1t)[i] = z;  // 16384 B
  for (int i = tid; i < 896;  i += 256) ((int4*)w2t)[i] = z;  // 14336 B
  __syncthreads();
  for (int idx = tid; idx < 5000; idx += 256) {  // W1 [100][50] -> rows=c cols=j
    int j = idx / 50, c = idx % 50;
    w1t[sw16(c, j >> 3) + (j & 7)] = (bf16)W1[idx];
  }
  for (int idx = tid; idx < 5000; idx += 256) {  // W2 [50][100] -> rows=jp cols=c
    int c = idx / 100, jp = idx % 100;
    w2t[sw8(jp, c >> 3) + (c & 7)] = (bf16)W2[idx];
  }
}

// ---------------- prep: mask -> additive bias rows [256][256] f32 ----------------
__global__ void k_maskbias(const void* __restrict__ maskp, const int* __restrict__ mode,
                           float* __restrict__ mb) {
  int b = blockIdx.x, col = threadIdx.x;
  int mmode = *mode;
  float v;
  if (col < NKk) v = 0.f;
  else if (col < 164) {
    int mi = b * 164 + col;
    long long m = (mmode == 1) ? (long long)((const unsigned char*)maskp)[mi]
                : (mmode == 0) ? (long long)((const int*)maskp)[mi]
                               : ((const long long*)maskp)[mi];
    v = m ? -__FLT_MAX__ : 0.f;
  } else v = -__FLT_MAX__;
  mb[b * 256 + col] = v;
}

// ---------------- transpose + convert: in (R x C f32) -> out (C x R bf16) ----------------
__global__ void k_transpose_cvt(const float* __restrict__ in, bf16* __restrict__ out,
                                int R, int C) {
  __shared__ float tile[32][33];
  int c0 = blockIdx.x * 32, r0 = blockIdx.y * 32;
  int tx = threadIdx.x & 31, ty = threadIdx.x >> 5;
#pragma unroll
  for (int i = 0; i < 4; ++i) {
    int r = ty + i * 8;
    tile[r][tx] = in[(size_t)(r0 + r) * C + c0 + tx];
  }
  __syncthreads();
#pragma unroll
  for (int i = 0; i < 4; ++i) {
    int rr = ty + i * 8;
    out[(size_t)(c0 + rr) * R + r0 + tx] = (bf16)tile[tx][rr];
  }
}

// ---------------- v transpose ----------------
__global__ void k_vT(const bf16* __restrict__ qkv, bf16* __restrict__ vT) {
  __shared__ bf16 t[32][33];
  int bh = blockIdx.y; int b = bh >> 3, h = bh & 7;
  int jt = blockIdx.x % 6, dt = blockIdx.x / 6;
  int tx = threadIdx.x & 31, ty = threadIdx.x >> 5;
#pragma unroll
  for (int i = 0; i < 4; ++i) {
    int j = jt * 32 + ty + i * 8;
    bf16 val = (bf16)0.f;
    if (j < 164) val = qkv[(size_t)(b * 164 + j) * 3072 + 2048 + h * 128 + dt * 32 + tx];
    t[ty + i * 8][tx] = val;
  }
  __syncthreads();
#pragma unroll
  for (int i = 0; i < 4; ++i) {
    int dh = dt * 32 + ty + i * 8;
    vT[((size_t)bh * 128 + dh) * JP + jt * 32 + tx] = t[tx][ty + i * 8];
  }
}

// ---------------- GEMM (as round 2) ----------------
template <int MODE>
__global__ __launch_bounds__(256) void k_gemm(const bf16* __restrict__ A,
                                              const bf16* __restrict__ Bt,
                                              void* __restrict__ Cout,
                                              const float* __restrict__ bias) {
  constexpr int K = 1024;
  constexpr int CLD = (MODE == 0) ? 3072 : 1024;
  __shared__ bf16 As[128 * 32];
  __shared__ bf16 Bs[128 * 32];
  const int tid = threadIdx.x, lane = tid & 63, w = tid >> 6;
  const int l15 = lane & 15, l4 = lane >> 4;
  const int wm = w >> 1, wn = w & 1;
  const int tileM = blockIdx.y * 128, tileN = blockIdx.x * 128;

  f32x4 acc[4][4];
#pragma unroll
  for (int mi = 0; mi < 4; ++mi)
#pragma unroll
    for (int ni = 0; ni < 4; ++ni) acc[mi][ni] = f32x4{0.f, 0.f, 0.f, 0.f};

  for (int k0 = 0; k0 < K; k0 += 32) {
    __syncthreads();
#pragma unroll
    for (int i = 0; i < 2; ++i) {
      int c = w * 2 + i;
      int blk = c * 64 + lane;
      int r = blk >> 2, sl = blk & 3;
      int kb = sl ^ ((r >> 1) & 3);
      gl_lds16(A + (size_t)(tileM + r) * K + k0 + kb * 8, (char*)As + c * 1024);
      gl_lds16(Bt + (size_t)(tileN + r) * K + k0 + kb * 8, (char*)Bs + c * 1024);
    }
    __syncthreads();
    bf16x8 af[4], bfr[4];
#pragma unroll
    for (int mi = 0; mi < 4; ++mi) {
      int r = wm * 64 + mi * 16 + l15;
      af[mi] = *(const bf16x8*)&As[r * 32 + ((l4 ^ ((r >> 1) & 3)) * 8)];
    }
#pragma unroll
    for (int ni = 0; ni < 4; ++ni) {
      int r = wn * 64 + ni * 16 + l15;
      bfr[ni] = *(const bf16x8*)&Bs[r * 32 + ((l4 ^ ((r >> 1) & 3)) * 8)];
    }
#pragma unroll
    for (int mi = 0; mi < 4; ++mi)
#pragma unroll
      for (int ni = 0; ni < 4; ++ni)
        acc[mi][ni] = __builtin_amdgcn_mfma_f32_16x16x32_bf16(af[mi], bfr[ni], acc[mi][ni], 0, 0, 0);
  }

#pragma unroll
  for (int mi = 0; mi < 4; ++mi)
#pragma unroll
    for (int ni = 0; ni < 4; ++ni)
#pragma unroll
      for (int j = 0; j < 4; ++j) {
        int m = tileM + wm * 64 + mi * 16 + l4 * 4 + j;
        int n = tileN + wn * 64 + ni * 16 + l15;
        float v = acc[mi][ni][j];
        if (MODE == 0)
          ((bf16*)Cout)[(size_t)m * CLD + n] = (bf16)v;
        else
          ((float*)Cout)[(size_t)m * CLD + n] = v + bias[n];
      }
}

// ---------------- fused attention: 512 threads, 8 waves ----------------
// LDS map (bytes):
//  [0,16384)        Qs  [64][128] sw16            (QK phase)
//  [16384,61440)    Ks  [176][128] sw16           (QK phase)
//  [0,49152)        VTs [128][192] sw24-rot       (overlays Qs/Ks after QK)
//  [61440,106752)   Ss  [64][177] f32  (stride 177 breaks 4-way bank conflict)
//  [106752,131328)  Ps  [64][192] sw24-rot ; first 16KB doubles as AQs [64][128] sw16
//  [131328,147712)  W1T [64][128] sw16 ; overlaid by H1s [64][64] sw8
//  [147712,162048)  W2T [112][64] sw8
//  [162048,163072)  bias row [256] f32
__global__ __launch_bounds__(512) void k_attn(
    const bf16* __restrict__ qkv, const bf16* __restrict__ vT,
    const bf16* __restrict__ w1t_g, const bf16* __restrict__ w2t_g,
    const float* __restrict__ maskbias, const float* __restrict__ xian,
    const float* __restrict__ b1, const float* __restrict__ b2,
    bf16* __restrict__ aout) {
  __shared__ __align__(16) char smem[163072];
  bf16* Qs  = (bf16*)smem;
  bf16* Ks  = (bf16*)(smem + 16384);
  bf16* VTs = (bf16*)smem;
  float* Ss = (float*)(smem + 61440);
  bf16* Ps  = (bf16*)(smem + 106752);
  bf16* AQs = (bf16*)(smem + 106752);
  bf16* W1T = (bf16*)(smem + 131328);
  bf16* H1s = (bf16*)(smem + 131328);
  bf16* W2T = (bf16*)(smem + 147712);
  float* biasL = (float*)(smem + 162048);

  const int tid = threadIdx.x, lane = tid & 63, w = tid >> 6;
  const int l15 = lane & 15, l4 = lane >> 4;
  const int wq = w & 3, wn = w >> 2;
  const int rq = wq * 16;
  const int qt = blockIdx.x, bh = blockIdx.y, b = bh >> 3, h = bh & 7;

  // ---- Phase 0: stage Q, K, W1T, W2T, bias ----
#pragma unroll
  for (int i = 0; i < 2; ++i) {
    int c = w * 2 + i;
    int blk = c * 64 + lane;
    int r = blk >> 4, sl = blk & 15;
    int kb = sl ^ (r & 7);
    int gi = qt * 64 + r; if (gi > 163) gi = 163;
    gl_lds16(qkv + (size_t)(b * 164 + gi) * 3072 + h * 128 + kb * 8, (char*)Qs + c * 1024);
  }
  for (int c = w; c < 41; c += 8) {
    int blk = c * 64 + lane;
    int r = blk >> 4, sl = blk & 15;
    int kb = sl ^ (r & 7);
    gl_lds16(qkv + (size_t)(b * 164 + r) * 3072 + 1024 + h * 128 + kb * 8, (char*)Ks + c * 1024);
  }
  for (int c = w; c < 16; c += 8)
    gl_lds16(w1t_g + c * 512 + lane * 8, (char*)W1T + c * 1024);
  for (int c = w; c < 14; c += 8)
    gl_lds16(w2t_g + c * 512 + lane * 8, (char*)W2T + c * 1024);
  if (w == 7)
    gl_lds16(maskbias + b * 256 + lane * 4, (char*)biasL);
  if (tid < 192) {  // zero K pad rows 164..175
    int r = 164 + (tid >> 4), sl = tid & 15;
    ((int4*)Ks)[r * 16 + sl] = make_int4(0, 0, 0, 0);
  }
  __syncthreads();

  // ---- Phase 1: S = Q K^T * scale + bias ; AQ = relu for qt<2 ----
  f32x4 accs[6];
#pragma unroll
  for (int i = 0; i < 6; ++i) accs[i] = f32x4{0.f, 0.f, 0.f, 0.f};
#pragma unroll
  for (int kk = 0; kk < 4; ++kk) {
    bf16x8 af = *(const bf16x8*)&Qs[sw16(rq + l15, kk * 4 + l4)];
#pragma unroll
    for (int i = 0; i < 6; ++i) {
      int nt = wn * 6 + i;
      if (nt < 11) {
        bf16x8 bb = *(const bf16x8*)&Ks[sw16(nt * 16 + l15, kk * 4 + l4)];
        accs[i] = __builtin_amdgcn_mfma_f32_16x16x32_bf16(af, bb, accs[i], 0, 0, 0);
      }
    }
  }
  constexpr float SC = 0.03125f;
#pragma unroll
  for (int i = 0; i < 6; ++i) {
    int nt = wn * 6 + i;
    if (nt < 11) {
      int col = nt * 16 + l15;
      float bv = biasL[col];
      bool aqw = (qt < 2) && (nt < 8);
#pragma unroll
      for (int j = 0; j < 4; ++j) {
        int row = rq + l4 * 4 + j;
        float v = accs[i][j] * SC + bv;
        Ss[row * 177 + col] = v;
        if (aqw)
          AQs[sw16(row, col >> 3) + (col & 7)] = (bf16)((col < NKk) ? fmaxf(v, 0.f) : 0.f);
      }
    }
  }
  __syncthreads();

  // ---- Phase 2: issue V stage (async, drains at a later barrier) ----
  for (int c = w; c < 48; c += 8) {
    int blk = c * 64 + lane;
    int dh = blk / 24, sl = blk % 24;
    int kb = sl - (dh % 24); if (kb < 0) kb += 24;
    gl_lds16(vT + ((size_t)bh * 128 + dh) * JP + kb * 8, (char*)VTs + c * 1024);
  }

  // ---- Phase 3: MLP via MFMA ----
  if (qt < 2) {
    f32x4 a1[2];
#pragma unroll
    for (int i = 0; i < 2; ++i) a1[i] = f32x4{0.f, 0.f, 0.f, 0.f};
#pragma unroll
    for (int kk = 0; kk < 4; ++kk) {
      bf16x8 af = *(const bf16x8*)&AQs[sw16(rq + l15, kk * 4 + l4)];
#pragma unroll
      for (int i = 0; i < 2; ++i) {
        int nt = wn * 2 + i;
        bf16x8 bb = *(const bf16x8*)&W1T[sw16(nt * 16 + l15, kk * 4 + l4)];
        a1[i] = __builtin_amdgcn_mfma_f32_16x16x32_bf16(af, bb, a1[i], 0, 0, 0);
      }
    }
    __syncthreads();  // everyone done reading W1T before H1s overlay
#pragma unroll
    for (int i = 0; i < 2; ++i) {
      int nt = wn * 2 + i;
      int c = nt * 16 + l15;
      float bb1 = (c < 50) ? b1[c] : 0.f;
#pragma unroll
      for (int j = 0; j < 4; ++j) {
        int row = rq + l4 * 4 + j;
        float hv = (c < 50) ? fmaxf(a1[i][j] + bb1, 0.f) : 0.f;
        H1s[sw8(row, c >> 3) + (c & 7)] = (bf16)hv;
      }
    }
    __syncthreads();
    f32x4 a2[4];
#pragma unroll
    for (int i = 0; i < 4; ++i) a2[i] = f32x4{0.f, 0.f, 0.f, 0.f};
#pragma unroll
    for (int kk = 0; kk < 2; ++kk) {
      bf16x8 af = *(const bf16x8*)&H1s[sw8(rq + l15, kk * 4 + l4)];
#pragma unroll
      for (int i = 0; i < 4; ++i) {
        int nt = wn * 4 + i;
        if (nt < 7) {
          bf16x8 bb = *(const bf16x8*)&W2T[sw8(nt * 16 + l15, kk * 4 + l4)];
          a2[i] = __builtin_amdgcn_mfma_f32_16x16x32_bf16(af, bb, a2[i], 0, 0, 0);
        }
      }
    }
#pragma unroll
    for (int i = 0; i < 4; ++i) {
      int nt = wn * 4 + i;
      if (nt < 7) {
        int jp = nt * 16 + l15;
        if (jp < NKk) {
          float bb2 = b2[jp];
#pragma unroll
          for (int j = 0; j < 4; ++j) {
            int row = rq + l4 * 4 + j;
            int gi = qt * 64 + row;
            if (gi < NKk) {
              float lv = fmaxf(a2[i][j] + bb2, 0.f);
              Ss[row * 177 + jp] += xian[((size_t)b * 100 + gi) * 100 + jp] * lv;
            }
          }
        }
      }
    }
  }
  __syncthreads();

  // ---- Phase 4: softmax (8 lanes/row, 22 cols each) ----
  {
    int row = tid >> 3, q8 = tid & 7;
    float* srow = &Ss[row * 177];
    int c0 = q8 * 22;
    float mx = -__FLT_MAX__;
    for (int cc = 0; cc < 22; ++cc) mx = fmaxf(mx, srow[c0 + cc]);
    mx = fmaxf(mx, __shfl_xor(mx, 1));
    mx = fmaxf(mx, __shfl_xor(mx, 2));
    mx = fmaxf(mx, __shfl_xor(mx, 4));
    float sum = 0.f;
    for (int cc = 0; cc < 22; ++cc) {
      float e = __expf(srow[c0 + cc] - mx);
      srow[c0 + cc] = e;
      sum += e;
    }
    sum += __shfl_xor(sum, 1);
    sum += __shfl_xor(sum, 2);
    sum += __shfl_xor(sum, 4);
    float rinv = 1.f / sum;
    int rmod = row % 24;
    for (int cc = 0; cc < 22; ++cc) {
      int col = c0 + cc;
      int s = (col >> 3) + rmod; if (s >= 24) s -= 24;
      Ps[row * 192 + s * 8 + (col & 7)] = (bf16)(srow[col] * rinv);
    }
    if (q8 == 7) {
#pragma unroll
      for (int col = 176; col < 192; ++col) {
        int s = (col >> 3) + rmod; if (s >= 24) s -= 24;
        Ps[row * 192 + s * 8 + (col & 7)] = (bf16)0.f;
      }
    }
  }
  __syncthreads();

  // ---- Phase 5: O = P V ----
  f32x4 ao[4];
#pragma unroll
  for (int i = 0; i < 4; ++i) ao[i] = f32x4{0.f, 0.f, 0.f, 0.f};
  int pm = (rq + l15) % 24;
  int vm[4];
#pragma unroll
  for (int i = 0; i < 4; ++i) vm[i] = ((wn * 4 + i) * 16 + l15) % 24;
#pragma unroll
  for (int kk = 0; kk < 6; ++kk) {
    int s = kk * 4 + l4;
    int sa = s + pm; if (sa >= 24) sa -= 24;
    bf16x8 af = *(const bf16x8*)&Ps[(rq + l15) * 192 + sa * 8];
#pragma unroll
    for (int i = 0; i < 4; ++i) {
      int vr = (wn * 4 + i) * 16 + l15;
      int sb = s + vm[i]; if (sb >= 24) sb -= 24;
      bf16x8 bb = *(const bf16x8*)&VTs[vr * 192 + sb * 8];
      ao[i] = __builtin_amdgcn_mfma_f32_16x16x32_bf16(af, bb, ao[i], 0, 0, 0);
    }
  }
#pragma unroll
  for (int i = 0; i < 4; ++i) {
    int dh = (wn * 4 + i) * 16 + l15;
#pragma unroll
    for (int j = 0; j < 4; ++j) {
      int row = rq + l4 * 4 + j;
      int gi = qt * 64 + row;
      if (gi < 164)
        aout[(size_t)(b * 164 + gi) * 1024 + h * 128 + dh] = (bf16)ao[i][j];
    }
  }
}

// ---------------- launch ----------------
extern "C" void kernel_launch(void* const* d_in, const int* in_sizes, int n_in,
                              void* d_out, int out_size, void* d_ws, size_t ws_size,
                              hipStream_t stream) {
  const float* x    = (const float*)d_in[0];
  const void* mask  = (const void*)d_in[1];
  const float* xian = (const float*)d_in[2];
  const float* Wqkv = (const float*)d_in[3];
  const float* W1   = (const float*)d_in[4];
  const float* b1   = (const float*)d_in[5];
  const float* W2   = (const float*)d_in[6];
  const float* b2   = (const float*)d_in[7];
  const float* Wout = (const float*)d_in[8];
  const float* bout = (const float*)d_in[9];
  float* out = (float*)d_out;
  char* ws = (char*)d_ws;

  // workspace layout (bytes)
  bf16* xb    = (bf16*)(ws);                    // [41984][1024]  (85,983,232 B)
  bf16* wqkvT = (bf16*)(ws + 85983232ULL);      // [3072][1024]
  bf16* woutT = (bf16*)(ws + 92274688ULL);      // [1024][1024]
  bf16* qkvb  = (bf16*)(ws + 94371840ULL);      // [41984][3072]
  bf16* vTb   = (bf16*)(ws + 352321536ULL);     // [2048][128][192]
  bf16* aoutb = (bf16*)(ws + 452984832ULL);     // [41984][1024]
  // prep scratch reuses xb region (dead after GEMM1, rewritten by cvt each call):
  int*   mmode    = (int*)(ws + 1024);
  bf16*  w1t_g    = (bf16*)(ws + 4096);         // 16384 B swizzled image
  bf16*  w2t_g    = (bf16*)(ws + 20480);        // 14336 B swizzled image
  float* maskbias = (float*)(ws + 36864);       // [256][256] f32

  k_cvt_bf16<<<2048, 256, 0, stream>>>(x, xb, Mm * 1024);
  k_transpose_cvt<<<dim3(96, 32), 256, 0, stream>>>(Wqkv, wqkvT, 1024, 3072);
  k_transpose_cvt<<<dim3(32, 32), 256, 0, stream>>>(Wout, woutT, 1024, 1024);
  k_gemm<0><<<dim3(24, 328), 256, 0, stream>>>(xb, wqkvT, (void*)qkvb, nullptr);
  k_maskdet<<<1, 256, 0, stream>>>((const unsigned char*)mask, mmode);
  k_prep_w<<<1, 256, 0, stream>>>(W1, W2, w1t_g, w2t_g);
  k_maskbias<<<256, 256, 0, stream>>>(mask, mmode, maskbias);
  k_vT<<<dim3(24, 2048), 256, 0, stream>>>(qkvb, vTb);
  k_attn<<<dim3(3, 2048), 512, 0, stream>>>(qkvb, vTb, w1t_g, w2t_g, maskbias, xian,
                                            b1, b2, aoutb);
  k_gemm<1><<<dim3(8, 328), 256, 0, stream>>>(aoutb, woutT, (void*)out, bout);
}

// Round 5
// 945.994 us; speedup vs baseline: 1.4729x; 1.1986x over previous
//
#include <hip/hip_runtime.h>
#include <hip/hip_bf16.h>
#include <cstdint>
#include <cstddef>

typedef __bf16 bf16;
typedef __attribute__((ext_vector_type(8))) __bf16 bf16x8;
typedef __attribute__((ext_vector_type(2))) __bf16 bf16x2;
typedef __attribute__((ext_vector_type(4))) __bf16 bf16x4;
typedef __attribute__((ext_vector_type(4))) float f32x4;

#define DEVI __device__ __forceinline__

constexpr int Bb = 256, Nn = 164, NKk = 100;
constexpr int Mm = Bb * Nn;   // 41984
constexpr int JP = 192;

DEVI void gl_lds16(const void* g, void* l) {
  __builtin_amdgcn_global_load_lds(
      (const __attribute__((address_space(1))) void*)g,
      (__attribute__((address_space(3))) void*)l, 16, 0, 0);
}

DEVI int sw16(int row, int kb) { return row * 128 + ((kb ^ (row & 7)) * 8); }
DEVI int sw8(int row, int kb)  { return row * 64 + ((kb ^ (row & 7)) * 8); }

// ---------------- convert f32 -> bf16 (flat) ----------------
__global__ void k_cvt_bf16(const float* __restrict__ in, bf16* __restrict__ out, int n) {
  int stride = gridDim.x * blockDim.x;
  for (int i = blockIdx.x * blockDim.x + threadIdx.x; i < (n >> 2); i += stride) {
    float4 v = ((const float4*)in)[i];
    bf16x4 o;
    o[0] = (bf16)v.x; o[1] = (bf16)v.y; o[2] = (bf16)v.z; o[3] = (bf16)v.w;
    ((bf16x4*)out)[i] = o;
  }
}

// ---------------- mask dtype detection ----------------
__global__ void k_maskdet(const unsigned char* __restrict__ m, int* __restrict__ mode) {
  __shared__ int sbyte, sodd;
  if (threadIdx.x == 0) { sbyte = 0; sodd = 0; }
  __syncthreads();
  for (int i = threadIdx.x; i < Mm; i += 256)
    if ((i & 3) && m[i]) sbyte = 1;
  __syncthreads();
  if (sbyte == 0) {
    const int* m32 = (const int*)m;
    for (int i = 1 + 2 * (int)threadIdx.x; i < Mm; i += 512)
      if (m32[i] != 0) sodd = 1;
  }
  __syncthreads();
  if (threadIdx.x == 0) *mode = sbyte ? 1 : (sodd ? 0 : 2);
}

// ---------------- prep: W1T/W2T swizzled bf16 LDS-images ----------------
__global__ void k_prep_w(const float* __restrict__ W1, const float* __restrict__ W2,
                         bf16* __restrict__ w1t, bf16* __restrict__ w2t) {
  int tid = threadIdx.x;
  int4 z = make_int4(0, 0, 0, 0);
  for (int i = tid; i < 1024; i += 256) ((int4*)w1t)[i] = z;  // 16384 B
  for (int i = tid; i < 896;  i += 256) ((int4*)w2t)[i] = z;  // 14336 B
  __syncthreads();
  for (int idx = tid; idx < 5000; idx += 256) {  // W1 [100][50] -> rows=c cols=k
    int k = idx / 50, c = idx % 50;
    w1t[sw16(c, k >> 3) + (k & 7)] = (bf16)W1[idx];
  }
  for (int idx = tid; idx < 5000; idx += 256) {  // W2 [50][100] -> rows=jp cols=c
    int c = idx / 100, jp = idx % 100;
    w2t[sw8(jp, c >> 3) + (c & 7)] = (bf16)W2[idx];
  }
}

// ---------------- prep: mask -> additive bias rows [256][192] f32 ----------------
__global__ void k_maskbias(const void* __restrict__ maskp, const int* __restrict__ mode,
                           float* __restrict__ mb) {
  int b = blockIdx.x, col = threadIdx.x;  // 192 threads
  int mmode = *mode;
  float v;
  if (col < NKk) v = 0.f;
  else if (col < 164) {
    int mi = b * 164 + col;
    long long m = (mmode == 1) ? (long long)((const unsigned char*)maskp)[mi]
                : (mmode == 0) ? (long long)((const int*)maskp)[mi]
                               : ((const long long*)maskp)[mi];
    v = m ? -__FLT_MAX__ : 0.f;
  } else v = -__FLT_MAX__;
  mb[b * 192 + col] = v;
}

// ---------------- prep: xian [b][gi][jp] -> xianT [b][jp][112-stride gi] ----------------
__global__ void k_xianT(const float* __restrict__ xian, float* __restrict__ xT) {
  __shared__ float t[32][33];
  int b = blockIdx.y;
  int gt = blockIdx.x & 3, jt = blockIdx.x >> 2;
  int tx = threadIdx.x & 31, ty = threadIdx.x >> 5;
#pragma unroll
  for (int i = 0; i < 4; ++i) {
    int gi = gt * 32 + ty + i * 8, jp = jt * 32 + tx;
    t[ty + i * 8][tx] = (gi < 100 && jp < 100) ? xian[((size_t)b * 100 + gi) * 100 + jp] : 0.f;
  }
  __syncthreads();
#pragma unroll
  for (int i = 0; i < 4; ++i) {
    int jp = jt * 32 + ty + i * 8, gi = gt * 32 + tx;
    if (jp < 100 && gi < 112)
      xT[((size_t)b * 100 + jp) * 112 + gi] = t[tx][ty + i * 8];
  }
}

// ---------------- transpose + convert: (R x C f32) -> (C x R bf16) ----------------
__global__ void k_transpose_cvt(const float* __restrict__ in, bf16* __restrict__ out,
                                int R, int C) {
  __shared__ float tile[32][33];
  int c0 = blockIdx.x * 32, r0 = blockIdx.y * 32;
  int tx = threadIdx.x & 31, ty = threadIdx.x >> 5;
#pragma unroll
  for (int i = 0; i < 4; ++i) {
    int r = ty + i * 8;
    tile[r][tx] = in[(size_t)(r0 + r) * C + c0 + tx];
  }
  __syncthreads();
#pragma unroll
  for (int i = 0; i < 4; ++i) {
    int rr = ty + i * 8;
    out[(size_t)(c0 + rr) * R + r0 + tx] = (bf16)tile[tx][rr];
  }
}

// ---------------- v transpose ----------------
__global__ void k_vT(const bf16* __restrict__ qkv, bf16* __restrict__ vT) {
  __shared__ bf16 t[32][33];
  int bh = blockIdx.y; int b = bh >> 3, h = bh & 7;
  int jt = blockIdx.x % 6, dt = blockIdx.x / 6;
  int tx = threadIdx.x & 31, ty = threadIdx.x >> 5;
#pragma unroll
  for (int i = 0; i < 4; ++i) {
    int j = jt * 32 + ty + i * 8;
    bf16 val = (bf16)0.f;
    if (j < 164) val = qkv[(size_t)(b * 164 + j) * 3072 + 2048 + h * 128 + dt * 32 + tx];
    t[ty + i * 8][tx] = val;
  }
  __syncthreads();
#pragma unroll
  for (int i = 0; i < 4; ++i) {
    int dh = dt * 32 + ty + i * 8;
    vT[((size_t)bh * 128 + dh) * JP + jt * 32 + tx] = t[tx][ty + i * 8];
  }
}

// ---------------- GEMM (unchanged) ----------------
template <int MODE>
__global__ __launch_bounds__(256) void k_gemm(const bf16* __restrict__ A,
                                              const bf16* __restrict__ Bt,
                                              void* __restrict__ Cout,
                                              const float* __restrict__ bias) {
  constexpr int K = 1024;
  constexpr int CLD = (MODE == 0) ? 3072 : 1024;
  __shared__ bf16 As[128 * 32];
  __shared__ bf16 Bs[128 * 32];
  const int tid = threadIdx.x, lane = tid & 63, w = tid >> 6;
  const int l15 = lane & 15, l4 = lane >> 4;
  const int wm = w >> 1, wn = w & 1;
  const int tileM = blockIdx.y * 128, tileN = blockIdx.x * 128;

  f32x4 acc[4][4];
#pragma unroll
  for (int mi = 0; mi < 4; ++mi)
#pragma unroll
    for (int ni = 0; ni < 4; ++ni) acc[mi][ni] = f32x4{0.f, 0.f, 0.f, 0.f};

  for (int k0 = 0; k0 < K; k0 += 32) {
    __syncthreads();
#pragma unroll
    for (int i = 0; i < 2; ++i) {
      int c = w * 2 + i;
      int blk = c * 64 + lane;
      int r = blk >> 2, sl = blk & 3;
      int kb = sl ^ ((r >> 1) & 3);
      gl_lds16(A + (size_t)(tileM + r) * K + k0 + kb * 8, (char*)As + c * 1024);
      gl_lds16(Bt + (size_t)(tileN + r) * K + k0 + kb * 8, (char*)Bs + c * 1024);
    }
    __syncthreads();
    bf16x8 af[4], bfr[4];
#pragma unroll
    for (int mi = 0; mi < 4; ++mi) {
      int r = wm * 64 + mi * 16 + l15;
      af[mi] = *(const bf16x8*)&As[r * 32 + ((l4 ^ ((r >> 1) & 3)) * 8)];
    }
#pragma unroll
    for (int ni = 0; ni < 4; ++ni) {
      int r = wn * 64 + ni * 16 + l15;
      bfr[ni] = *(const bf16x8*)&Bs[r * 32 + ((l4 ^ ((r >> 1) & 3)) * 8)];
    }
#pragma unroll
    for (int mi = 0; mi < 4; ++mi)
#pragma unroll
      for (int ni = 0; ni < 4; ++ni)
        acc[mi][ni] = __builtin_amdgcn_mfma_f32_16x16x32_bf16(af[mi], bfr[ni], acc[mi][ni], 0, 0, 0);
  }

#pragma unroll
  for (int mi = 0; mi < 4; ++mi)
#pragma unroll
    for (int ni = 0; ni < 4; ++ni)
#pragma unroll
      for (int j = 0; j < 4; ++j) {
        int m = tileM + wm * 64 + mi * 16 + l4 * 4 + j;
        int n = tileN + wn * 64 + ni * 16 + l15;
        float v = acc[mi][ni][j];
        if (MODE == 0)
          ((bf16*)Cout)[(size_t)m * CLD + n] = (bf16)v;
        else
          ((float*)Cout)[(size_t)m * CLD + n] = v + bias[n];
      }
}

// ---------------- fused attention: 1 block per bh, 11 waves, swapped-QK in-reg softmax ----
__global__ __launch_bounds__(704, 3) void k_attn(
    const bf16* __restrict__ qkv, const bf16* __restrict__ vT,
    const bf16* __restrict__ w1t_g, const bf16* __restrict__ w2t_g,
    const float* __restrict__ maskbias, const float* __restrict__ xianT,
    const float* __restrict__ b1, const float* __restrict__ b2,
    bf16* __restrict__ aout) {
  __shared__ __align__(16) char smem[160448];
  bf16* VTs = (bf16*)smem;
  bf16* Ks  = (bf16*)(smem + 49152);
  bf16* AQs = (bf16*)(smem + 49152);
  bf16* Pw0 = (bf16*)(smem + 94208);
  bf16* W1T = (bf16*)(smem + 128000);
  bf16* H1s = (bf16*)(smem + 128000);
  bf16* W2T = (bf16*)(smem + 144384);
  float* biasL = (float*)(smem + 158720);
  float* b1L = (float*)(smem + 159744);
  float* b2L = (float*)(smem + 160000);

  const int tid = threadIdx.x, lane = tid & 63, w = tid >> 6;  // w: 0..10
  const int l15 = lane & 15, l4 = lane >> 4;
  const int i0 = blockIdx.x;
  const int bh = (i0 & 7) * 256 + (i0 >> 3);   // XCD swizzle
  const int b = bh >> 3, h = bh & 7;
  const int rq = w * 16;
  const int pr12 = l15 % 12;   // rotation key for per-wave P slice (must be <12!)

  // Q fragments direct global -> regs (B-operand of swapped QK)
  bf16x8 qf[4];
  {
    int qrow = rq + l15; if (qrow > 163) qrow = 163;
    const bf16* qbase = qkv + (size_t)(b * 164 + qrow) * 3072 + h * 128;
#pragma unroll
    for (int kk = 0; kk < 4; ++kk)
      qf[kk] = *(const bf16x8*)(qbase + kk * 32 + l4 * 8);
  }

  // ---- stage K, V, W images, bias/b1/b2 ----
  for (int c = w; c < 41; c += 11) {
    int blk = c * 64 + lane;
    int r = blk >> 4, sl = blk & 15;
    int kb = sl ^ (r & 7);
    gl_lds16(qkv + (size_t)(b * 164 + r) * 3072 + 1024 + h * 128 + kb * 8, (char*)Ks + c * 1024);
  }
  for (int c = w; c < 48; c += 11) {
    int blk = c * 64 + lane;
    int dh = blk / 24, sl = blk % 24;
    int kb = sl - (dh % 24); if (kb < 0) kb += 24;
    gl_lds16(vT + ((size_t)bh * 128 + dh) * JP + kb * 8, (char*)VTs + c * 1024);
  }
  for (int c = w; c < 16; c += 11)
    gl_lds16(w1t_g + c * 512 + lane * 8, (char*)W1T + c * 1024);
  for (int c = w; c < 14; c += 11)
    gl_lds16(w2t_g + c * 512 + lane * 8, (char*)W2T + c * 1024);
  if (w == 10 && lane < 48)
    gl_lds16(maskbias + b * 192 + lane * 4, (char*)biasL);
  if (tid < 192) {  // zero K pad rows 164..175
    int r = 164 + (tid >> 4), sl = tid & 15;
    ((int4*)Ks)[r * 16 + sl] = make_int4(0, 0, 0, 0);
  }
  if (tid < 64) b1L[tid] = (tid < 50) ? b1[tid] : 0.f;
  else if (tid < 176) { int c = tid - 64; b2L[c] = (c < 100) ? b2[c] : 0.f; }
  __syncthreads();

  // ---- QK swapped: lane holds k = nt*16+l4*4+j for q = rq+l15 ----
  constexpr float SC = 0.03125f;
  f32x4 s[11];
#pragma unroll
  for (int nt = 0; nt < 11; ++nt) {
    f32x4 acc = f32x4{0.f, 0.f, 0.f, 0.f};
#pragma unroll
    for (int kk = 0; kk < 4; ++kk) {
      bf16x8 kf = *(const bf16x8*)&Ks[sw16(nt * 16 + l15, kk * 4 + l4)];
      acc = __builtin_amdgcn_mfma_f32_16x16x32_bf16(kf, qf[kk], acc, 0, 0, 0);
    }
    f32x4 bv = *(const f32x4*)&biasL[nt * 16 + l4 * 4];
#pragma unroll
    for (int j = 0; j < 4; ++j) acc[j] = acc[j] * SC + bv[j];
    s[nt] = acc;
  }
  __syncthreads();  // all K reads done -> AQ may overlay Ks

  // ---- AQ = relu(S[q<100][k<100]) as [q][128] bf16 sw16 (waves 0..6) ----
  if (w < 7) {
    int q = rq + l15;
#pragma unroll
    for (int nt = 0; nt < 8; ++nt) {
#pragma unroll
      for (int pr = 0; pr < 2; ++pr) {
        int k0 = nt * 16 + l4 * 4 + pr * 2;
        float v0 = (q < 100 && k0 < 100)     ? fmaxf(s[nt][pr * 2], 0.f)     : 0.f;
        float v1 = (q < 100 && k0 + 1 < 100) ? fmaxf(s[nt][pr * 2 + 1], 0.f) : 0.f;
        bf16x2 pv; pv[0] = (bf16)v0; pv[1] = (bf16)v1;
        *(bf16x2*)&AQs[sw16(q, k0 >> 3) + (k0 & 7)] = pv;
      }
    }
  }
  __syncthreads();

  // ---- MLP L1: H1^T[c][q] tiles, distributed over all waves ----
  f32x4 a1[3];
#pragma unroll
  for (int it = 0; it < 3; ++it) {
    int t = w + it * 11;
    f32x4 acc = f32x4{0.f, 0.f, 0.f, 0.f};
    if (t < 28) {
      int qs = t >> 2, ct = t & 3;
#pragma unroll
      for (int kk = 0; kk < 4; ++kk) {
        bf16x8 wf = *(const bf16x8*)&W1T[sw16(ct * 16 + l15, kk * 4 + l4)];
        bf16x8 af = *(const bf16x8*)&AQs[sw16(qs * 16 + l15, kk * 4 + l4)];
        acc = __builtin_amdgcn_mfma_f32_16x16x32_bf16(wf, af, acc, 0, 0, 0);
      }
    }
    a1[it] = acc;
  }
  __syncthreads();  // W1T reads done -> H1 overlay
#pragma unroll
  for (int it = 0; it < 3; ++it) {
    int t = w + it * 11;
    if (t < 28) {
      int qs = t >> 2, ct = t & 3;
      int qrow = qs * 16 + l15;
#pragma unroll
      for (int pr = 0; pr < 2; ++pr) {
        int c0 = ct * 16 + l4 * 4 + pr * 2;
        float v0 = (c0 < 50)     ? fmaxf(a1[it][pr * 2] + b1L[c0], 0.f)         : 0.f;
        float v1 = (c0 + 1 < 50) ? fmaxf(a1[it][pr * 2 + 1] + b1L[c0 + 1], 0.f) : 0.f;
        bf16x2 pv; pv[0] = (bf16)v0; pv[1] = (bf16)v1;
        *(bf16x2*)&H1s[sw8(qrow, c0 >> 3) + (c0 & 7)] = pv;
      }
    }
  }
  __syncthreads();  // H1 complete

  // ---- MLP L2 swapped: lv^T[jp][q] lands in same layout as s ----
  if (w < 7) {
    int q = rq + l15;
#pragma unroll
    for (int nt2 = 0; nt2 < 7; ++nt2) {
      f32x4 acc = f32x4{0.f, 0.f, 0.f, 0.f};
#pragma unroll
      for (int kk = 0; kk < 2; ++kk) {
        bf16x8 wf = *(const bf16x8*)&W2T[sw8(nt2 * 16 + l15, kk * 4 + l4)];
        bf16x8 hf = *(const bf16x8*)&H1s[sw8(rq + l15, kk * 4 + l4)];
        acc = __builtin_amdgcn_mfma_f32_16x16x32_bf16(wf, hf, acc, 0, 0, 0);
      }
#pragma unroll
      for (int j = 0; j < 4; ++j) {
        int jp = nt2 * 16 + l4 * 4 + j;
        if (jp < 100 && q < 100) {
          float lv = fmaxf(acc[j] + b2L[jp], 0.f);
          s[nt2][j] += xianT[((size_t)b * 100 + jp) * 112 + q] * lv;
        }
      }
    }
  }

  // ---- softmax fully in-register ----
  float mx = -__FLT_MAX__;
#pragma unroll
  for (int nt = 0; nt < 11; ++nt)
#pragma unroll
    for (int j = 0; j < 4; ++j) mx = fmaxf(mx, s[nt][j]);
  mx = fmaxf(mx, __shfl_xor(mx, 16));
  mx = fmaxf(mx, __shfl_xor(mx, 32));
  float sum = 0.f;
#pragma unroll
  for (int nt = 0; nt < 11; ++nt)
#pragma unroll
    for (int j = 0; j < 4; ++j) { float e = __expf(s[nt][j] - mx); s[nt][j] = e; sum += e; }
  sum += __shfl_xor(sum, 16);
  sum += __shfl_xor(sum, 32);
  float rinv = 1.f / sum;

  bf16x2 pp[11][2];
#pragma unroll
  for (int nt = 0; nt < 11; ++nt)
#pragma unroll
    for (int pr = 0; pr < 2; ++pr) {
      bf16x2 pv;
      pv[0] = (bf16)(s[nt][pr * 2] * rinv);
      pv[1] = (bf16)(s[nt][pr * 2 + 1] * rinv);
      pp[nt][pr] = pv;
    }

  // ---- PV in 2 k-halves via per-wave private P slice [16][96] mod-12 rot ----
  bf16* PwB = Pw0 + w * 1536;
  f32x4 o[8];
#pragma unroll
  for (int i = 0; i < 8; ++i) o[i] = f32x4{0.f, 0.f, 0.f, 0.f};
  int vmr[8];
#pragma unroll
  for (int i = 0; i < 8; ++i) vmr[i] = (i * 16 + l15) % 24;
#pragma unroll
  for (int hh = 0; hh < 2; ++hh) {
#pragma unroll
    for (int nn = 0; nn < 6; ++nn) {
      int nt = hh * 6 + nn;
      if (nt < 11) {
        int slot = nn * 2 + (l4 >> 1);
        int rs = slot + pr12; if (rs >= 12) rs -= 12;   // pr12<=11, slot<=11 -> one subtract ok
#pragma unroll
        for (int pr = 0; pr < 2; ++pr)
          *(bf16x2*)&PwB[l15 * 96 + rs * 8 + (l4 & 1) * 4 + pr * 2] = pp[nt][pr];
      }
    }
#pragma unroll
    for (int kk2 = 0; kk2 < 3; ++kk2) {
      int rs = kk2 * 4 + l4 + pr12; if (rs >= 12) rs -= 12;  // <=22 -> ok
      bf16x8 af = *(const bf16x8*)&PwB[l15 * 96 + rs * 8];
#pragma unroll
      for (int i = 0; i < 8; ++i) {
        int sb = 12 * hh + kk2 * 4 + l4 + vmr[i]; if (sb >= 24) sb -= 24;
        bf16x8 bb = *(const bf16x8*)&VTs[(i * 16 + l15) * 192 + sb * 8];
        o[i] = __builtin_amdgcn_mfma_f32_16x16x32_bf16(af, bb, o[i], 0, 0, 0);
      }
    }
  }

  // ---- store O ----
#pragma unroll
  for (int i = 0; i < 8; ++i) {
    int dh = i * 16 + l15;
#pragma unroll
    for (int j = 0; j < 4; ++j) {
      int q = rq + l4 * 4 + j;
      if (q < 164)
        aout[(size_t)(b * 164 + q) * 1024 + h * 128 + dh] = (bf16)o[i][j];
    }
  }
}

// ---------------- launch ----------------
extern "C" void kernel_launch(void* const* d_in, const int* in_sizes, int n_in,
                              void* d_out, int out_size, void* d_ws, size_t ws_size,
                              hipStream_t stream) {
  const float* x    = (const float*)d_in[0];
  const void* mask  = (const void*)d_in[1];
  const float* xian = (const float*)d_in[2];
  const float* Wqkv = (const float*)d_in[3];
  const float* W1   = (const float*)d_in[4];
  const float* b1   = (const float*)d_in[5];
  const float* W2   = (const float*)d_in[6];
  const float* b2   = (const float*)d_in[7];
  const float* Wout = (const float*)d_in[8];
  const float* bout = (const float*)d_in[9];
  float* out = (float*)d_out;
  char* ws = (char*)d_ws;

  // workspace layout (bytes)
  bf16* xb    = (bf16*)(ws);                    // [41984][1024]
  bf16* wqkvT = (bf16*)(ws + 85983232ULL);      // [3072][1024]
  bf16* woutT = (bf16*)(ws + 92274688ULL);      // [1024][1024]
  bf16* qkvb  = (bf16*)(ws + 94371840ULL);      // [41984][3072]
  bf16* vTb   = (bf16*)(ws + 352321536ULL);     // [2048][128][192]
  bf16* aoutb = (bf16*)(ws + 452984832ULL);     // [41984][1024]
  // prep scratch inside xb region (xb dead after GEMM1; preps run after GEMM1):
  int*   mmode    = (int*)(ws + 1024);
  bf16*  w1t_g    = (bf16*)(ws + 4096);         // 16384 B
  bf16*  w2t_g    = (bf16*)(ws + 20480);        // 14336 B
  float* maskbias = (float*)(ws + 36864);       // [256][192] f32
  float* xianTp   = (float*)(ws + 262144);      // [256*100][112] f32 ~ 11.5 MB

  k_cvt_bf16<<<2048, 256, 0, stream>>>(x, xb, Mm * 1024);
  k_transpose_cvt<<<dim3(96, 32), 256, 0, stream>>>(Wqkv, wqkvT, 1024, 3072);
  k_transpose_cvt<<<dim3(32, 32), 256, 0, stream>>>(Wout, woutT, 1024, 1024);
  k_gemm<0><<<dim3(24, 328), 256, 0, stream>>>(xb, wqkvT, (void*)qkvb, nullptr);
  k_maskdet<<<1, 256, 0, stream>>>((const unsigned char*)mask, mmode);
  k_prep_w<<<1, 256, 0, stream>>>(W1, W2, w1t_g, w2t_g);
  k_maskbias<<<256, 192, 0, stream>>>(mask, mmode, maskbias);
  k_xianT<<<dim3(16, 256), 256, 0, stream>>>(xian, xianTp);
  k_vT<<<dim3(24, 2048), 256, 0, stream>>>(qkvb, vTb);
  k_attn<<<2048, 704, 0, stream>>>(qkvb, vTb, w1t_g, w2t_g, maskbias, xianTp,
                                   b1, b2, aoutb);
  k_gemm<1><<<dim3(8, 328), 256, 0, stream>>>(aoutb, woutT, (void*)out, bout);
}